// Round 6
// baseline (198.092 us; speedup 1.0000x reference)
//
#include <hip/hip_runtime.h>
#include <hip/hip_bf16.h>
#include <math.h>

#define BB 4
#define NN 4096
#define CCH 256
#define HEADS 8
#define HD 32
#define NKV 1024
#define EPS_LN 1e-5f

typedef short short8 __attribute__((ext_vector_type(8)));
typedef float floatx4 __attribute__((ext_vector_type(4)));

// scale = HD^-0.5 folded with log2(e): softmax runs in exp2 domain
#define QSCALE (0.17677669529663687f * 1.4426950408889634f)

__device__ __forceinline__ unsigned pk_bf16(float a, float b) {
  __hip_bfloat162 h = __float22bfloat162_rn(make_float2(a, b));
  unsigned u; __builtin_memcpy(&u, &h, 4); return u;
}

__device__ __forceinline__ short8 cvt8(float4 a, float4 b) {
  union { short8 s; unsigned u[4]; } r;
  r.u[0] = pk_bf16(a.x, a.y); r.u[1] = pk_bf16(a.z, a.w);
  r.u[2] = pk_bf16(b.x, b.y); r.u[3] = pk_bf16(b.z, b.w);
  return r.s;
}

// ---------------------------------------------------------------------------
// Cast all four weight matrices fp32 -> bf16 (QSCALE folded into q_w).
// ---------------------------------------------------------------------------
__global__ __launch_bounds__(256) void cast_weights(
    const float* __restrict__ q_w, const float* __restrict__ kv_w,
    const float* __restrict__ sr_w, const float* __restrict__ proj_w,
    unsigned short* __restrict__ q_wbf, unsigned short* __restrict__ kv_wbf,
    unsigned short* __restrict__ sr_wbf, unsigned short* __restrict__ proj_wbf) {
  const long e0 = ((long)blockIdx.x * 256 + threadIdx.x) * 8;
  const float* src; unsigned short* dst; long off; float sc = 1.f;
  if (e0 < 65536)       { src = q_w;    dst = q_wbf;    off = e0;          sc = QSCALE; }
  else if (e0 < 196608) { src = kv_w;   dst = kv_wbf;   off = e0 - 65536; }
  else if (e0 < 458752) { src = sr_w;   dst = sr_wbf;   off = e0 - 196608; }
  else                  { src = proj_w; dst = proj_wbf; off = e0 - 458752; }
  float4 a = *(const float4*)&src[off];
  float4 b = *(const float4*)&src[off + 4];
  a.x *= sc; a.y *= sc; a.z *= sc; a.w *= sc;
  b.x *= sc; b.y *= sc; b.z *= sc; b.w *= sc;
  *(short8*)&dst[off] = cvt8(a, b);
}

// ===========================================================================
// 16-token GEMM machinery: block = 16 tokens x (waves x 64) channels.
// X tile (16 x 256 bf16) staged once into skewed LDS (33-unit row stride);
// W fragments streamed from L1/L2.
// ===========================================================================
#define XU16(t, u) (((t) * 33 + (u)) * 8)

template<int ORI>
__device__ __forceinline__ void gemm_core16(const unsigned short* xs,
    const unsigned short* wbase, int wrs, floatx4 acc[4], int l15, int qd) {
#pragma unroll
  for (int kc = 0; kc < 8; ++kc) {
    short8 xf = *(const short8*)(xs + XU16(l15, kc * 4 + qd));
#pragma unroll
    for (int ct = 0; ct < 4; ++ct) {
      short8 wf = *(const short8*)(wbase + (size_t)ct * 16 * wrs + kc * 32);
      if (ORI == 0)
        acc[ct] = __builtin_amdgcn_mfma_f32_16x16x32_bf16(wf, xf, acc[ct], 0, 0, 0);
      else
        acc[ct] = __builtin_amdgcn_mfma_f32_16x16x32_bf16(xf, wf, acc[ct], 0, 0, 0);
    }
  }
}

// ---------------------------------------------------------------------------
// Q projection: block = 16 tokens x 256 ch (4 waves). x staged ONCE.
// Grid 1024. Writes q_bf [b][h][tok][32] with QSCALE folded.
// ---------------------------------------------------------------------------
__global__ __launch_bounds__(256) void q_proj_gemm(const float* __restrict__ x,
    const unsigned short* __restrict__ q_wbf, const float* __restrict__ q_b,
    unsigned short* __restrict__ qbf) {
  __shared__ unsigned short xs[8448];   // 16 x 33 units
  const int tid = threadIdx.x, w = tid >> 6, ln = tid & 63;
  const int l15 = ln & 15, qd = ln >> 4;
  const long tok0 = (long)blockIdx.x * 16;
  const float* Xg = x + tok0 * 256;
#pragma unroll
  for (int j = 0; j < 2; ++j) {
    const int idx = j * 256 + tid;
    const int tok = idx >> 5, u = idx & 31;
    float4 a = *(const float4*)(Xg + (size_t)tok * 256 + u * 8);
    float4 b = *(const float4*)(Xg + (size_t)tok * 256 + u * 8 + 4);
    *(short8*)(xs + XU16(tok, u)) = cvt8(a, b);
  }
  __syncthreads();
  floatx4 acc[4];
#pragma unroll
  for (int ct = 0; ct < 4; ++ct) for (int r = 0; r < 4; ++r) acc[ct][r] = 0.f;
  const int chb = w * 64;
  const unsigned short* wbase = q_wbf + (size_t)(chb + l15) * 256 + qd * 8;
  gemm_core16<0>(xs, wbase, 256, acc, l15, qd);
  const int tok = (int)tok0 + l15;
  const int b = tok >> 12, trow = tok & 4095;
#pragma unroll
  for (int ct = 0; ct < 4; ++ct) {
    const int ch = chb + ct * 16 + qd * 4;
    float4 bb = *(const float4*)&q_b[ch];
    uint2 u;
    u.x = pk_bf16(acc[ct][0] + bb.x * QSCALE, acc[ct][1] + bb.y * QSCALE);
    u.y = pk_bf16(acc[ct][2] + bb.z * QSCALE, acc[ct][3] + bb.w * QSCALE);
    const int h = ch >> 5, d0 = ch & 31;
    *(uint2*)&qbf[((size_t)(b * HEADS + h) * NN + trow) * HD + d0] = u;
  }
}

// ---------------------------------------------------------------------------
// Fused SR-conv + LN: block = 16 kv tokens x 256 ch, 512 threads (8 waves):
// wave w -> K-half (w>>2), ch quarter ((w&3)*64). Cross-wave fp32 reduce in
// LDS, then 512-thread LN. Grid 256.
// ---------------------------------------------------------------------------
__global__ __launch_bounds__(512) void conv_ln_gemm(const float* __restrict__ x,
    const unsigned short* __restrict__ sr_wbf, const float* __restrict__ sr_b,
    const float* __restrict__ ln_g, const float* __restrict__ ln_b,
    unsigned short* __restrict__ xln) {
  __shared__ unsigned short sm[16512];   // 16 tok x 129 units = 33 KB
  const int tid = threadIdx.x, w = tid >> 6, lnn = tid & 63;
  const int l15 = lnn & 15, qd = lnn >> 4;
  const int half = w >> 2, chq = (w & 3) * 64;
  const int gt0 = blockIdx.x * 16;
  const int b = gt0 >> 10, tl = gt0 & 1023;
  // stage 16 tokens x 1024 patch feats (f = c*4 + di*2 + dj), bf16
#pragma unroll
  for (int j = 0; j < 4; ++j) {
    const int g = j * 512 + tid;
    const int tk = g >> 7, u = g & 127;
    const int c0 = u * 2;
    const int tt = tl + tk;
    const int ti = tt >> 5, tj = tt & 31;
    float4 va, vb;
    float* pa = (float*)&va; float* pb = (float*)&vb;
#pragma unroll
    for (int q = 0; q < 4; ++q) {
      const int row = (2 * ti + (q >> 1)) * 64 + 2 * tj + (q & 1);
      const float* s = &x[((size_t)b * NN + row) * CCH + c0];
      pa[q] = s[0]; pb[q] = s[1];
    }
    *(short8*)(sm + (tk * 129 + u) * 8) = cvt8(va, vb);
  }
  __syncthreads();
  floatx4 acc[4];
#pragma unroll
  for (int ct = 0; ct < 4; ++ct) for (int r = 0; r < 4; ++r) acc[ct][r] = 0.f;
  const unsigned short* wbase =
      sr_wbf + (size_t)(chq + l15) * 1024 + half * 512 + qd * 8;
#pragma unroll
  for (int kc = 0; kc < 16; ++kc) {
    short8 xf = *(const short8*)(sm + (l15 * 129 + half * 64 + kc * 4 + qd) * 8);
#pragma unroll
    for (int ct = 0; ct < 4; ++ct) {
      short8 wf = *(const short8*)(wbase + (size_t)ct * 16 * 1024 + kc * 32);
      acc[ct] = __builtin_amdgcn_mfma_f32_16x16x32_bf16(wf, xf, acc[ct], 0, 0, 0);
    }
  }
  __syncthreads();   // bf16 tile consumed
  float* ft = (float*)sm;   // [16][260]
  if (half == 1) {
#pragma unroll
    for (int ct = 0; ct < 4; ++ct) {
      float4 o;
      o.x = acc[ct][0]; o.y = acc[ct][1]; o.z = acc[ct][2]; o.w = acc[ct][3];
      *(float4*)&ft[l15 * 260 + chq + ct * 16 + qd * 4] = o;
    }
  }
  __syncthreads();
  if (half == 0) {
#pragma unroll
    for (int ct = 0; ct < 4; ++ct) {
      float* p = &ft[l15 * 260 + chq + ct * 16 + qd * 4];
      float4 o = *(float4*)p;
      o.x += acc[ct][0]; o.y += acc[ct][1]; o.z += acc[ct][2]; o.w += acc[ct][3];
      *(float4*)p = o;
    }
  }
  __syncthreads();
  // LN: thread = (token tk, 8-ch slice l32)
  const int tk = tid >> 5, l32 = tid & 31;
  float4 va = *(float4*)&ft[tk * 260 + l32 * 8];
  float4 vb = *(float4*)&ft[tk * 260 + l32 * 8 + 4];
  float4 sba = *(const float4*)&sr_b[l32 * 8];
  float4 sbb = *(const float4*)&sr_b[l32 * 8 + 4];
  va.x += sba.x; va.y += sba.y; va.z += sba.z; va.w += sba.w;
  vb.x += sbb.x; vb.y += sbb.y; vb.z += sbb.z; vb.w += sbb.w;
  float s1 = va.x + va.y + va.z + va.w + vb.x + vb.y + vb.z + vb.w;
  float s2 = va.x * va.x + va.y * va.y + va.z * va.z + va.w * va.w
           + vb.x * vb.x + vb.y * vb.y + vb.z * vb.z + vb.w * vb.w;
#pragma unroll
  for (int off = 1; off < 32; off <<= 1) {
    s1 += __shfl_xor(s1, off);
    s2 += __shfl_xor(s2, off);
  }
  const float mu = s1 * (1.f / 256.f);
  const float rstd = rsqrtf(s2 * (1.f / 256.f) - mu * mu + EPS_LN);
  float4 ga = *(const float4*)&ln_g[l32 * 8];
  float4 gb = *(const float4*)&ln_g[l32 * 8 + 4];
  float4 ba = *(const float4*)&ln_b[l32 * 8];
  float4 bb = *(const float4*)&ln_b[l32 * 8 + 4];
  unsigned ou[4];
  ou[0] = pk_bf16((va.x - mu) * rstd * ga.x + ba.x, (va.y - mu) * rstd * ga.y + ba.y);
  ou[1] = pk_bf16((va.z - mu) * rstd * ga.z + ba.z, (va.w - mu) * rstd * ga.w + ba.w);
  ou[2] = pk_bf16((vb.x - mu) * rstd * gb.x + bb.x, (vb.y - mu) * rstd * gb.y + bb.y);
  ou[3] = pk_bf16((vb.z - mu) * rstd * gb.z + bb.z, (vb.w - mu) * rstd * gb.w + bb.w);
  *(uint4*)&xln[((size_t)gt0 + tk) * 256 + l32 * 8] = *(uint4*)&ou[0];
}

// ---------------------------------------------------------------------------
// KV projection: block = 16 kv tokens x 512 ch, 512 threads. xln staged ONCE.
// waves 0-3 -> K channels (lane=token layout), 4-7 -> V (transposed to vT).
// Grid 256.
// ---------------------------------------------------------------------------
__global__ __launch_bounds__(512) void kv_gemm(const unsigned short* __restrict__ xln,
    const unsigned short* __restrict__ kv_wbf, const float* __restrict__ kv_b,
    unsigned short* __restrict__ kbf, unsigned short* __restrict__ vtbf) {
  __shared__ unsigned short xs[8448];
  const int tid = threadIdx.x, w = tid >> 6, ln = tid & 63;
  const int l15 = ln & 15, qd = ln >> 4;
  const int gt0 = blockIdx.x * 16;
  {  // stage 512 units with 512 threads
    const int tok = tid >> 5, u = tid & 31;
    *(uint4*)(xs + XU16(tok, u)) =
        *(const uint4*)(xln + ((size_t)gt0 + tok) * 256 + u * 8);
  }
  __syncthreads();
  const bool isV = (w >= 4);
  const int chb = (w & 3) * 64 + (isV ? 256 : 0);
  floatx4 acc[4];
#pragma unroll
  for (int ct = 0; ct < 4; ++ct) for (int r = 0; r < 4; ++r) acc[ct][r] = 0.f;
  const unsigned short* wbase = kv_wbf + (size_t)(chb + l15) * 256 + qd * 8;
  const int b = gt0 >> 10, tl = gt0 & 1023;
  if (!isV) {
    gemm_core16<0>(xs, wbase, 256, acc, l15, qd);
    const int tok = tl + l15;
#pragma unroll
    for (int ct = 0; ct < 4; ++ct) {
      const int ch = chb + ct * 16 + qd * 4;
      float4 bb = *(const float4*)&kv_b[ch];
      uint2 u;
      u.x = pk_bf16(acc[ct][0] + bb.x, acc[ct][1] + bb.y);
      u.y = pk_bf16(acc[ct][2] + bb.z, acc[ct][3] + bb.w);
      const int h = ch >> 5, d0 = ch & 31;
      *(uint2*)&kbf[((size_t)(b * HEADS + h) * NKV + tok) * HD + d0] = u;
    }
  } else {
    gemm_core16<1>(xs, wbase, 256, acc, l15, qd);
#pragma unroll
    for (int ct = 0; ct < 4; ++ct) {
      const int vc = chb - 256 + ct * 16 + l15;
      const float bb = kv_b[vc + 256];
      uint2 u;
      u.x = pk_bf16(acc[ct][0] + bb, acc[ct][1] + bb);
      u.y = pk_bf16(acc[ct][2] + bb, acc[ct][3] + bb);
      const int h = vc >> 5, d = vc & 31;
      *(uint2*)&vtbf[((size_t)(b * HEADS + h) * HD + d) * NKV + tl + qd * 4] = u;
    }
  }
}

// ---------------------------------------------------------------------------
// MFMA flash attention v5: 128 queries/block; K fragments read ONCE per
// chunk and shared across both query tiles (s0,s1 computed back-to-back).
// Native v_exp_f32, fragment-major conflict-free LDS, no-max softmax.
// Grid (32, 8, 4).
// ---------------------------------------------------------------------------
__global__ __launch_bounds__(256) void attn_mfma(
    const unsigned short* __restrict__ qbf,
    const unsigned short* __restrict__ kbf,
    const unsigned short* __restrict__ vtbf,
    unsigned short* __restrict__ abf) {
  __shared__ unsigned short sm[16896];
  const int tid = threadIdx.x, w = tid >> 6, ln = tid & 63;
  const int l15 = ln & 15, qd = ln >> 4;
  const int h = blockIdx.y, b = blockIdx.z;
  const int bh = b * HEADS + h;
  const unsigned short* kbase = kbf + (size_t)bh * NKV * HD;
  const unsigned short* vtbase = vtbf + (size_t)bh * HD * NKV;
  const int q0 = blockIdx.x * 128 + w * 16 + l15;
  short8 qf0 = *(const short8*)(qbf + ((size_t)bh * NN + q0) * HD + qd * 8);
  short8 qf1 = *(const short8*)(qbf + ((size_t)bh * NN + q0 + 64) * HD + qd * 8);
  floatx4 acc[2][2];
#pragma unroll
  for (int qt = 0; qt < 2; ++qt)
#pragma unroll
    for (int i = 0; i < 2; ++i)
#pragma unroll
      for (int r = 0; r < 4; ++r) acc[qt][i][r] = 0.f;
  float lr[2] = {0.f, 0.f};
  const int pu = 1024 + w * 272;

  for (int cc = 0; cc < 8; ++cc) {
    const int t0 = cc * 128;
    __syncthreads();
#pragma unroll
    for (int it = 0; it < 4; ++it) {
      const int idx = it * 256 + tid;
      const unsigned short* src;
      if (idx < 512) {   // K [128 keys][32d] fragment order
        const int t = idx >> 6, l = idx & 63;
        src = kbase + (size_t)(t0 + t * 16 + (l & 15)) * HD + (l >> 4) * 8;
      } else {           // Vt [32d][128 keys] fragment order
        const int j = idx - 512;
        const int kg = j >> 7, half = (j >> 6) & 1, qdd = (j >> 4) & 3, dl = j & 15;
        src = vtbase + (size_t)(half * 16 + dl) * NKV + t0 + kg * 32 + qdd * 8;
      }
      *(uint4*)(sm + idx * 8) = *(const uint4*)src;
    }
    __syncthreads();

    // QK for both query tiles off a single K-fragment read
    floatx4 s0[8], s1[8];
#pragma unroll
    for (int t = 0; t < 8; ++t) {
      short8 kf = *(const short8*)(sm + (t * 64 + ln) * 8);
      floatx4 z; for (int r = 0; r < 4; ++r) z[r] = 0.f;
      s0[t] = __builtin_amdgcn_mfma_f32_16x16x32_bf16(kf, qf0, z, 0, 0, 0);
      s1[t] = __builtin_amdgcn_mfma_f32_16x16x32_bf16(kf, qf1, z, 0, 0, 0);
    }
#pragma unroll
    for (int qt = 0; qt < 2; ++qt) {
      const floatx4* s = (qt == 0) ? s0 : s1;
      float lacc = 0.f;
#pragma unroll
      for (int t = 0; t < 8; ++t) {
        const float p0 = __builtin_amdgcn_exp2f(s[t][0]);
        const float p1 = __builtin_amdgcn_exp2f(s[t][1]);
        const float p2 = __builtin_amdgcn_exp2f(s[t][2]);
        const float p3 = __builtin_amdgcn_exp2f(s[t][3]);
        lacc += (p0 + p1) + (p2 + p3);
        uint2 pk;
        pk.x = pk_bf16(p0, p1);
        pk.y = pk_bf16(p2, p3);
        const int unit = pu + (t >> 1) * 68 + ((t & 1) * 2 + (qd >> 1)) * 16 + l15;
        *(uint2*)(sm + unit * 8 + (qd & 1) * 4) = pk;
      }
      lr[qt] += lacc;
#pragma unroll
      for (int kg = 0; kg < 4; ++kg) {
        short8 pf = *(const short8*)(sm + (pu + kg * 68 + ln) * 8);
        short8 v0 = *(const short8*)(sm + (512 + kg * 128 + ln) * 8);
        short8 v1 = *(const short8*)(sm + (512 + kg * 128 + 64 + ln) * 8);
        acc[qt][0] = __builtin_amdgcn_mfma_f32_16x16x32_bf16(v0, pf, acc[qt][0], 0, 0, 0);
        acc[qt][1] = __builtin_amdgcn_mfma_f32_16x16x32_bf16(v1, pf, acc[qt][1], 0, 0, 0);
      }
    }
  }
#pragma unroll
  for (int qt = 0; qt < 2; ++qt) {
    float lt = lr[qt];
    lt += __shfl_xor(lt, 16);
    lt += __shfl_xor(lt, 32);
    const float inv = 1.f / lt;
    unsigned short* obase = abf + ((size_t)b * NN + q0 + qt * 64) * CCH + h * HD;
    uint2 u0, u1;
    u0.x = pk_bf16(acc[qt][0][0] * inv, acc[qt][0][1] * inv);
    u0.y = pk_bf16(acc[qt][0][2] * inv, acc[qt][0][3] * inv);
    u1.x = pk_bf16(acc[qt][1][0] * inv, acc[qt][1][1] * inv);
    u1.y = pk_bf16(acc[qt][1][2] * inv, acc[qt][1][3] * inv);
    *(uint2*)(obase + qd * 4) = u0;
    *(uint2*)(obase + 16 + qd * 4) = u1;
  }
}

// ---------------------------------------------------------------------------
// Output projection: block = 16 tokens x 256 ch (4 waves); attn_bf staged
// ONCE. Grid 1024. fp32 out.
// ---------------------------------------------------------------------------
__global__ __launch_bounds__(256) void proj_gemm(const unsigned short* __restrict__ abf,
    const unsigned short* __restrict__ p_wbf, const float* __restrict__ p_b,
    float* __restrict__ out) {
  __shared__ unsigned short xs[8448];
  const int tid = threadIdx.x, w = tid >> 6, ln = tid & 63;
  const int l15 = ln & 15, qd = ln >> 4;
  const long tok0 = (long)blockIdx.x * 16;
#pragma unroll
  for (int j = 0; j < 2; ++j) {
    const int idx = j * 256 + tid;
    const int tok = idx >> 5, u = idx & 31;
    *(uint4*)(xs + XU16(tok, u)) =
        *(const uint4*)(abf + (tok0 + tok) * 256 + u * 8);
  }
  __syncthreads();
  floatx4 acc[4];
#pragma unroll
  for (int ct = 0; ct < 4; ++ct) for (int r = 0; r < 4; ++r) acc[ct][r] = 0.f;
  const int chb = w * 64;
  const unsigned short* wbase = p_wbf + (size_t)(chb + l15) * 256 + qd * 8;
  gemm_core16<0>(xs, wbase, 256, acc, l15, qd);
  const long tok = tok0 + l15;
#pragma unroll
  for (int ct = 0; ct < 4; ++ct) {
    const int ch = chb + ct * 16 + qd * 4;
    float4 bb = *(const float4*)&p_b[ch];
    float4 o;
    o.x = acc[ct][0] + bb.x; o.y = acc[ct][1] + bb.y;
    o.z = acc[ct][2] + bb.z; o.w = acc[ct][3] + bb.w;
    *(float4*)&out[(size_t)tok * 256 + ch] = o;
  }
}

// ---------------------------------------------------------------------------
extern "C" void kernel_launch(void* const* d_in, const int* in_sizes, int n_in,
                              void* d_out, int out_size, void* d_ws, size_t ws_size,
                              hipStream_t stream) {
  const float* x      = (const float*)d_in[0];
  const float* q_w    = (const float*)d_in[1];
  const float* q_b    = (const float*)d_in[2];
  const float* kv_w   = (const float*)d_in[3];
  const float* kv_b   = (const float*)d_in[4];
  const float* sr_w   = (const float*)d_in[5];
  const float* sr_b   = (const float*)d_in[6];
  const float* ln_g   = (const float*)d_in[7];
  const float* ln_b   = (const float*)d_in[8];
  const float* proj_w = (const float*)d_in[9];
  const float* proj_b = (const float*)d_in[10];
  float* out = (float*)d_out;

  char* base = (char*)d_ws;
  const size_t MB = 1048576;
  unsigned short* q_wbf    = (unsigned short*)(base);                 // 128 KB
  unsigned short* kv_wbf   = (unsigned short*)(base + 131072);        // 256 KB
  unsigned short* sr_wbf   = (unsigned short*)(base + 393216);        // 512 KB
  unsigned short* proj_wbf = (unsigned short*)(base + 917504);        // 128 KB
  unsigned short* q_bf     = (unsigned short*)(base + 1 * MB);        // 8 MB
  unsigned short* k_bf     = (unsigned short*)(base + 9 * MB);        // 2 MB
  unsigned short* vt_bf    = (unsigned short*)(base + 11 * MB);       // 2 MB
  unsigned short* xln      = (unsigned short*)(base + 13 * MB);       // 2 MB
  unsigned short* attn_bf  = (unsigned short*)(base + 15 * MB);       // 8 MB

  cast_weights<<<256, 256, 0, stream>>>(q_w, kv_w, sr_w, proj_w,
                                        q_wbf, kv_wbf, sr_wbf, proj_wbf);
  q_proj_gemm<<<1024, 256, 0, stream>>>(x, q_wbf, q_b, q_bf);
  conv_ln_gemm<<<256, 512, 0, stream>>>(x, sr_wbf, sr_b, ln_g, ln_b, xln);
  kv_gemm<<<256, 512, 0, stream>>>(xln, kv_wbf, kv_b, k_bf, vt_bf);
  attn_mfma<<<dim3(32, HEADS, BB), 256, 0, stream>>>(q_bf, k_bf, vt_bf, attn_bf);
  proj_gemm<<<1024, 256, 0, stream>>>(attn_bf, proj_wbf, proj_b, out);
}

// Round 7
// 158.481 us; speedup vs baseline: 1.2499x; 1.2499x over previous
//
#include <hip/hip_runtime.h>
#include <hip/hip_bf16.h>
#include <math.h>

#define BB 4
#define NN 4096
#define CCH 256
#define HEADS 8
#define HD 32
#define NKV 1024
#define EPS_LN 1e-5f

typedef short short8 __attribute__((ext_vector_type(8)));
typedef float floatx4 __attribute__((ext_vector_type(4)));

// scale = HD^-0.5 folded with log2(e): softmax runs in exp2 domain
#define QSCALE (0.17677669529663687f * 1.4426950408889634f)

__device__ __forceinline__ unsigned pk_bf16(float a, float b) {
  __hip_bfloat162 h = __float22bfloat162_rn(make_float2(a, b));
  unsigned u; __builtin_memcpy(&u, &h, 4); return u;
}

__device__ __forceinline__ short8 cvt8(float4 a, float4 b) {
  union { short8 s; unsigned u[4]; } r;
  r.u[0] = pk_bf16(a.x, a.y); r.u[1] = pk_bf16(a.z, a.w);
  r.u[2] = pk_bf16(b.x, b.y); r.u[3] = pk_bf16(b.z, b.w);
  return r.s;
}

// async global->LDS, 16B per lane; lptr must be the wave-uniform base
__device__ __forceinline__ void gl_lds16(const unsigned short* g, unsigned short* l) {
  __builtin_amdgcn_global_load_lds(
      (const __attribute__((address_space(1))) void*)g,
      (__attribute__((address_space(3))) void*)l, 16, 0, 0);
}

// ---------------------------------------------------------------------------
// Cast weights fp32 -> bf16 into FRAGMENT-MAJOR swizzled layout:
// unit(row,col) = ((row>>4)*(Kd/32) + (col>>5))*64 + ((col>>3)&3)*16 + (row&15)
// so a wave's wf load (lane = qd*16+l15) is one contiguous 1KB segment.
// QSCALE folded into q_w.
// ---------------------------------------------------------------------------
__global__ __launch_bounds__(256) void cast_weights(
    const float* __restrict__ q_w, const float* __restrict__ kv_w,
    const float* __restrict__ sr_w, const float* __restrict__ proj_w,
    unsigned short* __restrict__ q_wbf, unsigned short* __restrict__ kv_wbf,
    unsigned short* __restrict__ sr_wbf, unsigned short* __restrict__ proj_wbf) {
  const int e = (blockIdx.x * 256 + threadIdx.x) * 8;
  const float* src; unsigned short* dst; int off; int shift, kdu; float sc = 1.f;
  if (e < 65536)       { src = q_w;    dst = q_wbf;    off = e;          shift = 8;  kdu = 8;  sc = QSCALE; }
  else if (e < 196608) { src = kv_w;   dst = kv_wbf;   off = e - 65536;  shift = 8;  kdu = 8; }
  else if (e < 458752) { src = sr_w;   dst = sr_wbf;   off = e - 196608; shift = 10; kdu = 32; }
  else                 { src = proj_w; dst = proj_wbf; off = e - 458752; shift = 8;  kdu = 8; }
  const int row = off >> shift;
  const int col = off & ((1 << shift) - 1);
  const int unit = ((row >> 4) * kdu + (col >> 5)) * 64 + ((col >> 3) & 3) * 16 + (row & 15);
  float4 a = *(const float4*)&src[off];
  float4 b = *(const float4*)&src[off + 4];
  a.x *= sc; a.y *= sc; a.z *= sc; a.w *= sc;
  b.x *= sc; b.y *= sc; b.z *= sc; b.w *= sc;
  *(short8*)&dst[unit * 8] = cvt8(a, b);
}

// X-tile LDS layout (16 tokens x 32 16B-units, 33-unit skew)
#define XU16(t, u) (((t) * 33 + (u)) * 8)

// ---------------------------------------------------------------------------
// Q projection: block = 16 tokens x 256 ch (4 waves), x staged once.
// Swizzled W: contiguous 1KB wf loads. Grid 1024.
// ---------------------------------------------------------------------------
__global__ __launch_bounds__(256) void q_proj_gemm(const float* __restrict__ x,
    const unsigned short* __restrict__ q_wbf, const float* __restrict__ q_b,
    unsigned short* __restrict__ qbf) {
  __shared__ unsigned short xs[8448];
  const int tid = threadIdx.x, w = tid >> 6, ln = tid & 63;
  const int l15 = ln & 15, qd = ln >> 4;
  const long tok0 = (long)blockIdx.x * 16;
  const float* Xg = x + tok0 * 256;
#pragma unroll
  for (int j = 0; j < 2; ++j) {
    const int idx = j * 256 + tid;
    const int tok = idx >> 5, u = idx & 31;
    float4 a = *(const float4*)(Xg + (size_t)tok * 256 + u * 8);
    float4 b = *(const float4*)(Xg + (size_t)tok * 256 + u * 8 + 4);
    *(short8*)(xs + XU16(tok, u)) = cvt8(a, b);
  }
  __syncthreads();
  floatx4 acc[4];
#pragma unroll
  for (int ct = 0; ct < 4; ++ct) for (int r = 0; r < 4; ++r) acc[ct][r] = 0.f;
  // rt0 = w*4 ; wf(ct,kc) at ((rt0+ct)*8+kc)*64 + lane  (units)
  const unsigned short* wb = q_wbf + (size_t)(w * 4) * 4096 + ln * 8;
#pragma unroll
  for (int kc = 0; kc < 8; ++kc) {
    short8 xf = *(const short8*)(xs + XU16(l15, kc * 4 + qd));
#pragma unroll
    for (int ct = 0; ct < 4; ++ct) {
      short8 wf = *(const short8*)(wb + (ct * 8 + kc) * 512);
      acc[ct] = __builtin_amdgcn_mfma_f32_16x16x32_bf16(wf, xf, acc[ct], 0, 0, 0);
    }
  }
  const int tok = (int)tok0 + l15;
  const int b = tok >> 12, trow = tok & 4095;
  const int chb = w * 64;
#pragma unroll
  for (int ct = 0; ct < 4; ++ct) {
    const int ch = chb + ct * 16 + qd * 4;
    float4 bb = *(const float4*)&q_b[ch];
    uint2 u;
    u.x = pk_bf16(acc[ct][0] + bb.x * QSCALE, acc[ct][1] + bb.y * QSCALE);
    u.y = pk_bf16(acc[ct][2] + bb.z * QSCALE, acc[ct][3] + bb.w * QSCALE);
    const int h = ch >> 5, d0 = ch & 31;
    *(uint2*)&qbf[((size_t)(b * HEADS + h) * NN + trow) * HD + d0] = u;
  }
}

// ---------------------------------------------------------------------------
// Fused SR-conv (K=1024 patch-merge) + LN + KV projection.
// Block = 16 kv tokens, 512 threads (8 waves). Phase 1: conv split-K across
// wave halves, cross-wave fp32 reduce, LN -> xln tile kept in LDS.
// Phase 2: KV GEMM from the LDS tile (waves 0-3 K-chs, 4-7 V-chs).
// Grid 256.
// ---------------------------------------------------------------------------
__global__ __launch_bounds__(512) void convkv_gemm(const float* __restrict__ x,
    const unsigned short* __restrict__ sr_wbf, const float* __restrict__ sr_b,
    const float* __restrict__ ln_g, const float* __restrict__ ln_b,
    const unsigned short* __restrict__ kv_wbf, const float* __restrict__ kv_b,
    unsigned short* __restrict__ kbf, unsigned short* __restrict__ vtbf) {
  __shared__ unsigned short sm[16512];       // patch 16x129 units = 33KB
  unsigned short* xs = sm + 8704;            // byte 17408: xln tile 16x33 units
  const int tid = threadIdx.x, w = tid >> 6, lnn = tid & 63;
  const int l15 = lnn & 15, qd = lnn >> 4;
  const int half = w >> 2, chq = (w & 3) * 64;
  const int gt0 = blockIdx.x * 16;
  const int b = gt0 >> 10, tl = gt0 & 1023;
  // stage 16 tokens x 1024 patch feats (f = c*4 + di*2 + dj), bf16
#pragma unroll
  for (int j = 0; j < 4; ++j) {
    const int g = j * 512 + tid;
    const int tk = g >> 7, u = g & 127;
    const int c0 = u * 2;
    const int tt = tl + tk;
    const int ti = tt >> 5, tj = tt & 31;
    float4 va, vb;
    float* pa = (float*)&va; float* pb = (float*)&vb;
#pragma unroll
    for (int q = 0; q < 4; ++q) {
      const int row = (2 * ti + (q >> 1)) * 64 + 2 * tj + (q & 1);
      const float* s = &x[((size_t)b * NN + row) * CCH + c0];
      pa[q] = s[0]; pb[q] = s[1];
    }
    *(short8*)(sm + (tk * 129 + u) * 8) = cvt8(va, vb);
  }
  __syncthreads();
  floatx4 acc[4];
#pragma unroll
  for (int ct = 0; ct < 4; ++ct) for (int r = 0; r < 4; ++r) acc[ct][r] = 0.f;
  // swizzled sr_w (Kd=1024): wf(ct,kc) at ((rt0+ct)*32 + half*16 + kc)*64 + lane
  const unsigned short* wbc =
      sr_wbf + ((size_t)((w & 3) * 4 * 32 + half * 16) * 64 + lnn) * 8;
#pragma unroll
  for (int kc = 0; kc < 16; ++kc) {
    short8 xf = *(const short8*)(sm + (l15 * 129 + half * 64 + kc * 4 + qd) * 8);
#pragma unroll
    for (int ct = 0; ct < 4; ++ct) {
      short8 wf = *(const short8*)(wbc + ct * 16384 + kc * 512);
      acc[ct] = __builtin_amdgcn_mfma_f32_16x16x32_bf16(wf, xf, acc[ct], 0, 0, 0);
    }
  }
  __syncthreads();   // bf16 patch consumed
  float* ft = (float*)sm;   // [16][260] fp32
  if (half == 1) {
#pragma unroll
    for (int ct = 0; ct < 4; ++ct) {
      float4 o;
      o.x = acc[ct][0]; o.y = acc[ct][1]; o.z = acc[ct][2]; o.w = acc[ct][3];
      *(float4*)&ft[l15 * 260 + chq + ct * 16 + qd * 4] = o;
    }
  }
  __syncthreads();
  if (half == 0) {
#pragma unroll
    for (int ct = 0; ct < 4; ++ct) {
      float* p = &ft[l15 * 260 + chq + ct * 16 + qd * 4];
      float4 o = *(float4*)p;
      o.x += acc[ct][0]; o.y += acc[ct][1]; o.z += acc[ct][2]; o.w += acc[ct][3];
      *(float4*)p = o;
    }
  }
  __syncthreads();
  // LN: thread = (token tk, 8-ch slice l32) -> write xln tile into xs (LDS)
  {
    const int tk = tid >> 5, l32 = tid & 31;
    float4 va = *(float4*)&ft[tk * 260 + l32 * 8];
    float4 vb = *(float4*)&ft[tk * 260 + l32 * 8 + 4];
    float4 sba = *(const float4*)&sr_b[l32 * 8];
    float4 sbb = *(const float4*)&sr_b[l32 * 8 + 4];
    va.x += sba.x; va.y += sba.y; va.z += sba.z; va.w += sba.w;
    vb.x += sbb.x; vb.y += sbb.y; vb.z += sbb.z; vb.w += sbb.w;
    float s1 = va.x + va.y + va.z + va.w + vb.x + vb.y + vb.z + vb.w;
    float s2 = va.x * va.x + va.y * va.y + va.z * va.z + va.w * va.w
             + vb.x * vb.x + vb.y * vb.y + vb.z * vb.z + vb.w * vb.w;
#pragma unroll
    for (int off = 1; off < 32; off <<= 1) {
      s1 += __shfl_xor(s1, off);
      s2 += __shfl_xor(s2, off);
    }
    const float mu = s1 * (1.f / 256.f);
    const float rstd = rsqrtf(s2 * (1.f / 256.f) - mu * mu + EPS_LN);
    float4 ga = *(const float4*)&ln_g[l32 * 8];
    float4 gb = *(const float4*)&ln_g[l32 * 8 + 4];
    float4 ba = *(const float4*)&ln_b[l32 * 8];
    float4 bb = *(const float4*)&ln_b[l32 * 8 + 4];
    float4 oa, ob;
    oa.x = (va.x - mu) * rstd * ga.x + ba.x; oa.y = (va.y - mu) * rstd * ga.y + ba.y;
    oa.z = (va.z - mu) * rstd * ga.z + ba.z; oa.w = (va.w - mu) * rstd * ga.w + ba.w;
    ob.x = (vb.x - mu) * rstd * gb.x + bb.x; ob.y = (vb.y - mu) * rstd * gb.y + bb.y;
    ob.z = (vb.z - mu) * rstd * gb.z + bb.z; ob.w = (vb.w - mu) * rstd * gb.w + bb.w;
    *(short8*)(xs + XU16(tk, l32)) = cvt8(oa, ob);
  }
  __syncthreads();
  // Phase 2: KV GEMM from xs
  const bool isV = (w >= 4);
  const int chb = (w & 3) * 64 + (isV ? 256 : 0);
  floatx4 kacc[4];
#pragma unroll
  for (int ct = 0; ct < 4; ++ct) for (int r = 0; r < 4; ++r) kacc[ct][r] = 0.f;
  const unsigned short* wb = kv_wbf + (size_t)(chb >> 4) * 4096 + lnn * 8;
  if (!isV) {
#pragma unroll
    for (int kc = 0; kc < 8; ++kc) {
      short8 xf = *(const short8*)(xs + XU16(l15, kc * 4 + qd));
#pragma unroll
      for (int ct = 0; ct < 4; ++ct) {
        short8 wf = *(const short8*)(wb + (ct * 8 + kc) * 512);
        kacc[ct] = __builtin_amdgcn_mfma_f32_16x16x32_bf16(wf, xf, kacc[ct], 0, 0, 0);
      }
    }
    const int tok = tl + l15;
#pragma unroll
    for (int ct = 0; ct < 4; ++ct) {
      const int ch = chb + ct * 16 + qd * 4;
      float4 bb = *(const float4*)&kv_b[ch];
      uint2 u;
      u.x = pk_bf16(kacc[ct][0] + bb.x, kacc[ct][1] + bb.y);
      u.y = pk_bf16(kacc[ct][2] + bb.z, kacc[ct][3] + bb.w);
      const int h = ch >> 5, d0 = ch & 31;
      *(uint2*)&kbf[((size_t)(b * HEADS + h) * NKV + tok) * HD + d0] = u;
    }
  } else {
#pragma unroll
    for (int kc = 0; kc < 8; ++kc) {
      short8 xf = *(const short8*)(xs + XU16(l15, kc * 4 + qd));
#pragma unroll
      for (int ct = 0; ct < 4; ++ct) {
        short8 wf = *(const short8*)(wb + (ct * 8 + kc) * 512);
        kacc[ct] = __builtin_amdgcn_mfma_f32_16x16x32_bf16(xf, wf, kacc[ct], 0, 0, 0);
      }
    }
#pragma unroll
    for (int ct = 0; ct < 4; ++ct) {
      const int vc = chb - 256 + ct * 16 + l15;
      const float bb = kv_b[vc + 256];
      uint2 u;
      u.x = pk_bf16(kacc[ct][0] + bb, kacc[ct][1] + bb);
      u.y = pk_bf16(kacc[ct][2] + bb, kacc[ct][3] + bb);
      const int h = vc >> 5, d = vc & 31;
      *(uint2*)&vtbf[((size_t)(b * HEADS + h) * HD + d) * NKV + tl + qd * 4] = u;
    }
  }
}

// ---------------------------------------------------------------------------
// MFMA flash attention v6: 64-key chunks (16 iters), double-buffered K/V
// staged with global_load_lds (issued right after each barrier -> drains
// during compute), V fragments shared across both query tiles, l computed
// via ones-fragment MFMA. One barrier per chunk. Grid (32, 8, 4).
// LDS: buf0[0,512) buf1[512,1024) units; P at 1024 + w*272 + qt*136.
// ---------------------------------------------------------------------------
__global__ __launch_bounds__(256) void attn_mfma(
    const unsigned short* __restrict__ qbf,
    const unsigned short* __restrict__ kbf,
    const unsigned short* __restrict__ vtbf,
    unsigned short* __restrict__ abf) {
  __shared__ unsigned short sm[16896];   // 2112 units
  const int tid = threadIdx.x, w = tid >> 6, ln = tid & 63;
  const int l15 = ln & 15, qd = ln >> 4;
  const int h = blockIdx.y, b = blockIdx.z;
  const int bh = b * HEADS + h;
  const unsigned short* kbase = kbf + (size_t)bh * NKV * HD;
  const unsigned short* vtbase = vtbf + (size_t)bh * HD * NKV;
  const int q0 = blockIdx.x * 128 + w * 16 + l15;
  const short8 qf0 = *(const short8*)(qbf + ((size_t)bh * NN + q0) * HD + qd * 8);
  const short8 qf1 = *(const short8*)(qbf + ((size_t)bh * NN + q0 + 64) * HD + qd * 8);
  const short8 ones = {16256, 16256, 16256, 16256, 16256, 16256, 16256, 16256};
  floatx4 a00, a01, a10, a11, al0, al1;
#pragma unroll
  for (int r = 0; r < 4; ++r) {
    a00[r] = 0.f; a01[r] = 0.f; a10[r] = 0.f; a11[r] = 0.f;
    al0[r] = 0.f; al1[r] = 0.f;
  }
  const int pb0 = 1024 + w * 272;
  const int pb1 = pb0 + 136;

  // prologue: stage chunk 0 into buf0
#pragma unroll
  for (int it = 0; it < 2; ++it) {
    const unsigned short* src;
    if (w < 2) {
      const int t = w * 2 + it;
      src = kbase + (size_t)(t * 16 + l15) * HD + qd * 8;
    } else {
      src = vtbase + (size_t)(it * 16 + l15) * NKV + (w - 2) * 32 + qd * 8;
    }
    gl_lds16(src, sm + (w * 128 + it * 64) * 8);
  }

  for (int cc = 0; cc < 16; ++cc) {
    __syncthreads();   // drains this chunk's staging; fences buffer reuse
    const int cb = (cc & 1) * 512;
    if (cc < 15) {     // stage next chunk into the other buffer (overlaps compute)
      const int sb = 512 - cb;
      const int t0n = (cc + 1) * 64;
#pragma unroll
      for (int it = 0; it < 2; ++it) {
        const unsigned short* src;
        if (w < 2) {
          const int t = w * 2 + it;
          src = kbase + (size_t)(t0n + t * 16 + l15) * HD + qd * 8;
        } else {
          src = vtbase + (size_t)(it * 16 + l15) * NKV + t0n + (w - 2) * 32 + qd * 8;
        }
        gl_lds16(src, sm + (sb + w * 128 + it * 64) * 8);
      }
    }
    // QK: 4 key tiles, both query tiles off one kf read
    floatx4 s0[4], s1[4];
#pragma unroll
    for (int t = 0; t < 4; ++t) {
      short8 kf = *(const short8*)(sm + (cb + t * 64 + ln) * 8);
      floatx4 z; for (int r = 0; r < 4; ++r) z[r] = 0.f;
      s0[t] = __builtin_amdgcn_mfma_f32_16x16x32_bf16(kf, qf0, z, 0, 0, 0);
      s1[t] = __builtin_amdgcn_mfma_f32_16x16x32_bf16(kf, qf1, z, 0, 0, 0);
    }
    // exp2 + pack + store P (no max, no scalar l-sum)
#pragma unroll
    for (int t = 0; t < 4; ++t) {
      const int uoff = (t >> 1) * 68 + ((t & 1) * 2 + (qd >> 1)) * 16 + l15;
      uint2 pk;
      pk.x = pk_bf16(__builtin_amdgcn_exp2f(s0[t][0]), __builtin_amdgcn_exp2f(s0[t][1]));
      pk.y = pk_bf16(__builtin_amdgcn_exp2f(s0[t][2]), __builtin_amdgcn_exp2f(s0[t][3]));
      *(uint2*)(sm + (pb0 + uoff) * 8 + (qd & 1) * 4) = pk;
      pk.x = pk_bf16(__builtin_amdgcn_exp2f(s1[t][0]), __builtin_amdgcn_exp2f(s1[t][1]));
      pk.y = pk_bf16(__builtin_amdgcn_exp2f(s1[t][2]), __builtin_amdgcn_exp2f(s1[t][3]));
      *(uint2*)(sm + (pb1 + uoff) * 8 + (qd & 1) * 4) = pk;
    }
    // PV: V fragments shared across qt; l via ones-MFMA
#pragma unroll
    for (int kg = 0; kg < 2; ++kg) {
      short8 v0 = *(const short8*)(sm + (cb + 256 + kg * 128 + ln) * 8);
      short8 v1 = *(const short8*)(sm + (cb + 256 + kg * 128 + 64 + ln) * 8);
      short8 pf0 = *(const short8*)(sm + (pb0 + kg * 68 + ln) * 8);
      short8 pf1 = *(const short8*)(sm + (pb1 + kg * 68 + ln) * 8);
      a00 = __builtin_amdgcn_mfma_f32_16x16x32_bf16(v0, pf0, a00, 0, 0, 0);
      a01 = __builtin_amdgcn_mfma_f32_16x16x32_bf16(v1, pf0, a01, 0, 0, 0);
      a10 = __builtin_amdgcn_mfma_f32_16x16x32_bf16(v0, pf1, a10, 0, 0, 0);
      a11 = __builtin_amdgcn_mfma_f32_16x16x32_bf16(v1, pf1, a11, 0, 0, 0);
      al0 = __builtin_amdgcn_mfma_f32_16x16x32_bf16(ones, pf0, al0, 0, 0, 0);
      al1 = __builtin_amdgcn_mfma_f32_16x16x32_bf16(ones, pf1, al1, 0, 0, 0);
    }
  }
  // al[.] every reg/lane holds the full l for its query column
  {
    const float inv = 1.f / al0[0];
    unsigned short* ob = abf + ((size_t)b * NN + q0) * CCH + h * HD;
    uint2 u0, u1;
    u0.x = pk_bf16(a00[0] * inv, a00[1] * inv);
    u0.y = pk_bf16(a00[2] * inv, a00[3] * inv);
    u1.x = pk_bf16(a01[0] * inv, a01[1] * inv);
    u1.y = pk_bf16(a01[2] * inv, a01[3] * inv);
    *(uint2*)(ob + qd * 4) = u0;
    *(uint2*)(ob + 16 + qd * 4) = u1;
  }
  {
    const float inv = 1.f / al1[0];
    unsigned short* ob = abf + ((size_t)b * NN + q0 + 64) * CCH + h * HD;
    uint2 u0, u1;
    u0.x = pk_bf16(a10[0] * inv, a10[1] * inv);
    u0.y = pk_bf16(a10[2] * inv, a10[3] * inv);
    u1.x = pk_bf16(a11[0] * inv, a11[1] * inv);
    u1.y = pk_bf16(a11[2] * inv, a11[3] * inv);
    *(uint2*)(ob + qd * 4) = u0;
    *(uint2*)(ob + 16 + qd * 4) = u1;
  }
}

// ---------------------------------------------------------------------------
// Output projection: block = 16 tokens x 256 ch (4 waves), swizzled W.
// Grid 1024, fp32 out.
// ---------------------------------------------------------------------------
__global__ __launch_bounds__(256) void proj_gemm(const unsigned short* __restrict__ abf,
    const unsigned short* __restrict__ p_wbf, const float* __restrict__ p_b,
    float* __restrict__ out) {
  __shared__ unsigned short xs[8448];
  const int tid = threadIdx.x, w = tid >> 6, ln = tid & 63;
  const int l15 = ln & 15, qd = ln >> 4;
  const long tok0 = (long)blockIdx.x * 16;
#pragma unroll
  for (int j = 0; j < 2; ++j) {
    const int idx = j * 256 + tid;
    const int tok = idx >> 5, u = idx & 31;
    *(uint4*)(xs + XU16(tok, u)) =
        *(const uint4*)(abf + (tok0 + tok) * 256 + u * 8);
  }
  __syncthreads();
  floatx4 acc[4];
#pragma unroll
  for (int ct = 0; ct < 4; ++ct) for (int r = 0; r < 4; ++r) acc[ct][r] = 0.f;
  const unsigned short* wb = p_wbf + (size_t)(w * 4) * 4096 + ln * 8;
#pragma unroll
  for (int kc = 0; kc < 8; ++kc) {
    short8 xf = *(const short8*)(xs + XU16(l15, kc * 4 + qd));
#pragma unroll
    for (int ct = 0; ct < 4; ++ct) {
      short8 wf = *(const short8*)(wb + (ct * 8 + kc) * 512);
      acc[ct] = __builtin_amdgcn_mfma_f32_16x16x32_bf16(wf, xf, acc[ct], 0, 0, 0);
    }
  }
  const long tok = tok0 + l15;
  const int chb = w * 64;
#pragma unroll
  for (int ct = 0; ct < 4; ++ct) {
    const int ch = chb + ct * 16 + qd * 4;
    float4 bb = *(const float4*)&p_b[ch];
    float4 o;
    o.x = acc[ct][0] + bb.x; o.y = acc[ct][1] + bb.y;
    o.z = acc[ct][2] + bb.z; o.w = acc[ct][3] + bb.w;
    *(float4*)&out[(size_t)tok * 256 + ch] = o;
  }
}

// ---------------------------------------------------------------------------
extern "C" void kernel_launch(void* const* d_in, const int* in_sizes, int n_in,
                              void* d_out, int out_size, void* d_ws, size_t ws_size,
                              hipStream_t stream) {
  const float* x      = (const float*)d_in[0];
  const float* q_w    = (const float*)d_in[1];
  const float* q_b    = (const float*)d_in[2];
  const float* kv_w   = (const float*)d_in[3];
  const float* kv_b   = (const float*)d_in[4];
  const float* sr_w   = (const float*)d_in[5];
  const float* sr_b   = (const float*)d_in[6];
  const float* ln_g   = (const float*)d_in[7];
  const float* ln_b   = (const float*)d_in[8];
  const float* proj_w = (const float*)d_in[9];
  const float* proj_b = (const float*)d_in[10];
  float* out = (float*)d_out;

  char* base = (char*)d_ws;
  const size_t MB = 1048576;
  unsigned short* q_wbf    = (unsigned short*)(base);                 // 128 KB
  unsigned short* kv_wbf   = (unsigned short*)(base + 131072);        // 256 KB
  unsigned short* sr_wbf   = (unsigned short*)(base + 393216);        // 512 KB
  unsigned short* proj_wbf = (unsigned short*)(base + 917504);        // 128 KB
  unsigned short* q_bf     = (unsigned short*)(base + 1 * MB);        // 8 MB
  unsigned short* k_bf     = (unsigned short*)(base + 9 * MB);        // 2 MB
  unsigned short* vt_bf    = (unsigned short*)(base + 11 * MB);       // 2 MB
  unsigned short* attn_bf  = (unsigned short*)(base + 13 * MB);       // 8 MB

  cast_weights<<<256, 256, 0, stream>>>(q_w, kv_w, sr_w, proj_w,
                                        q_wbf, kv_wbf, sr_wbf, proj_wbf);
  q_proj_gemm<<<1024, 256, 0, stream>>>(x, q_wbf, q_b, q_bf);
  convkv_gemm<<<256, 512, 0, stream>>>(x, sr_wbf, sr_b, ln_g, ln_b,
                                       kv_wbf, kv_b, k_bf, vt_bf);
  attn_mfma<<<dim3(32, HEADS, BB), 256, 0, stream>>>(q_bf, k_bf, vt_bf, attn_bf);
  proj_gemm<<<1024, 256, 0, stream>>>(attn_bf, proj_wbf, proj_b, out);
}